// Round 2
// baseline (445.753 us; speedup 1.0000x reference)
//
#include <hip/hip_runtime.h>
#include <cstdint>
#include <cstddef>

typedef _Float16 f16;
typedef __attribute__((ext_vector_type(8))) _Float16 f16x8;
typedef __attribute__((ext_vector_type(2))) _Float16 f16x2;
typedef __attribute__((ext_vector_type(4))) float f32x4;

#define MFMA_F16(a, b, c) __builtin_amdgcn_mfma_f32_16x16x32_f16((a), (b), (c), 0, 0, 0)

// ---------------------------------------------------------------------------
// k0: convert the three 512x512 fp32 weight matrices to f16 in workspace.
// layout in ws (f16): [0..262143]=W_left, [262144..]=W_right, [524288..]=W_out
// ---------------------------------------------------------------------------
__global__ void k0_cvt(const float* __restrict__ wl, const float* __restrict__ wr,
                       const float* __restrict__ wo, f16* __restrict__ dst) {
    int i = blockIdx.x * 256 + threadIdx.x;   // 0 .. 262143
    dst[i]          = (f16)wl[i];
    dst[262144 + i] = (f16)wr[i];
    dst[524288 + i] = (f16)wo[i];
}

// ---------------------------------------------------------------------------
// k1: vec_left = x@W_L^T + b_L(e0), vec_right = x@W_R^T + b_R(e0), gp = GP(l,r)
// gp stored f16 into d_out: batch b's region = d_out + b*16384 bytes,
//   blade plane i at +i*1024, channel n at +n*2  (linear; k2 swizzles on stage)
// Block tile: 32 batches x 64 channels, BK=32, 8 waves (each 16x16), dbuf LDS.
// ---------------------------------------------------------------------------
__global__ __launch_bounds__(512, 4) void k1_gp(
    const float* __restrict__ x, const f16* __restrict__ wf,
    const float* __restrict__ bl_p, const float* __restrict__ br_p,
    char* gp_out)
{
    __shared__ __align__(16) f16 As[2][8][32*32];   // [buf][blade][b][m] 32KB
    __shared__ __align__(16) f16 Ws[2][2][64*32];   // [buf][side][n][m]  16KB

    // XCD-chunked swizzle: all 8 channel-tiles of a batch-tile on one XCD,
    // temporally adjacent -> x tile (512KB) stays in that XCD's L2.
    const int L   = blockIdx.x;          // 0..4095
    const int xcd = L & 7, sl = L >> 3;  // sl 0..511
    const int bt  = xcd * 64 + (sl >> 3);
    const int ct  = sl & 7;
    const int b0  = bt * 32;
    const int n0  = ct * 64;

    const int tid  = threadIdx.x;
    const int lane = tid & 63;
    const int wv   = tid >> 6;
    const int wb   = wv >> 2, wn = wv & 3;
    const int r_lo = lane & 15, s_hi = lane >> 4;

    f32x4 accL[8], accR[8];
    const f32x4 zero = {0.f, 0.f, 0.f, 0.f};
#pragma unroll
    for (int i = 0; i < 8; ++i) { accL[i] = zero; accR[i] = zero; }

    // staging maps (fixed per thread)
    const int sbb = tid >> 4, smg = tid & 15;                 // x: batch row, m-pair
    const int abase = sbb * 32 + (((smg >> 2) ^ (sbb & 3)) << 3) + ((2 * smg) & 7);
    const int wside = tid >> 8, wnl = (tid >> 2) & 63, wc = tid & 3;
    const int wbase = wnl * 32 + ((wc ^ (wnl & 3)) << 3);
    const float* xsrc0 = x + ((size_t)(b0 + sbb) * 512 + 2 * smg) * 8;
    const f16*   wsrc0 = wf + (size_t)wside * (512 * 512) + (size_t)(n0 + wnl) * 512 + wc * 8;

    auto stage = [&](int kk, int buf) {
        const float* src = xsrc0 + (size_t)kk * 256;          // m0 = kk*32 -> *8 floats
        f32x4 a0 = *(const f32x4*)(src);
        f32x4 a1 = *(const f32x4*)(src + 4);
        f32x4 a2 = *(const f32x4*)(src + 8);
        f32x4 a3 = *(const f32x4*)(src + 12);
#pragma unroll
        for (int i = 0; i < 4; ++i) {
            f16x2 p; p[0] = (f16)a0[i]; p[1] = (f16)a2[i];
            *(f16x2*)&As[buf][i][abase] = p;
            f16x2 q; q[0] = (f16)a1[i]; q[1] = (f16)a3[i];
            *(f16x2*)&As[buf][i + 4][abase] = q;
        }
        f16x8 w8 = *(const f16x8*)(wsrc0 + kk * 32);
        *(f16x8*)&Ws[buf][wside][wbase] = w8;
    };

    const int ar   = wb * 16 + r_lo;
    const int aoff = ar * 32 + ((s_hi ^ (ar & 3)) << 3);
    const int nloc = wn * 16 + r_lo;
    const int boff = nloc * 32 + ((s_hi ^ (nloc & 3)) << 3);

    stage(0, 0);
    for (int kk = 0; kk < 16; ++kk) {
        __syncthreads();
        if (kk < 15) stage(kk + 1, (kk + 1) & 1);
        const int buf = kk & 1;
        f16x8 bL = *(const f16x8*)&Ws[buf][0][boff];
        f16x8 bR = *(const f16x8*)&Ws[buf][1][boff];
#pragma unroll
        for (int i = 0; i < 8; ++i) {
            f16x8 a = *(const f16x8*)&As[buf][i][aoff];
            accL[i] = MFMA_F16(a, bL, accL[i]);
            accR[i] = MFMA_F16(a, bR, accR[i]);
        }
    }

    const int n_g = n0 + nloc;
    const float blv = bl_p[n_g], brv = br_p[n_g];
#pragma unroll
    for (int rr = 0; rr < 4; ++rr) {
        const int b_g = b0 + wb * 16 + s_hi * 4 + rr;
        float Lv[8], Rv[8];
#pragma unroll
        for (int i = 0; i < 8; ++i) { Lv[i] = accL[i][rr]; Rv[i] = accR[i][rr]; }
        Lv[0] += blv; Rv[0] += brv;
        // Cl(3,0) geometric product, blades [1,e1,e2,e3,e12,e13,e23,e123]
        float g[8];
        g[0] = Lv[0]*Rv[0]+Lv[1]*Rv[1]+Lv[2]*Rv[2]+Lv[3]*Rv[3]-Lv[4]*Rv[4]-Lv[5]*Rv[5]-Lv[6]*Rv[6]-Lv[7]*Rv[7];
        g[1] = Lv[0]*Rv[1]+Lv[1]*Rv[0]-Lv[2]*Rv[4]-Lv[3]*Rv[5]+Lv[4]*Rv[2]+Lv[5]*Rv[3]-Lv[6]*Rv[7]-Lv[7]*Rv[6];
        g[2] = Lv[0]*Rv[2]+Lv[1]*Rv[4]+Lv[2]*Rv[0]-Lv[3]*Rv[6]-Lv[4]*Rv[1]+Lv[5]*Rv[7]+Lv[6]*Rv[3]+Lv[7]*Rv[5];
        g[3] = Lv[0]*Rv[3]+Lv[1]*Rv[5]+Lv[2]*Rv[6]+Lv[3]*Rv[0]-Lv[4]*Rv[7]-Lv[5]*Rv[1]-Lv[6]*Rv[2]-Lv[7]*Rv[4];
        g[4] = Lv[0]*Rv[4]+Lv[1]*Rv[2]-Lv[2]*Rv[1]+Lv[3]*Rv[7]+Lv[4]*Rv[0]-Lv[5]*Rv[6]+Lv[6]*Rv[5]+Lv[7]*Rv[3];
        g[5] = Lv[0]*Rv[5]+Lv[1]*Rv[3]-Lv[2]*Rv[7]-Lv[3]*Rv[1]+Lv[4]*Rv[6]+Lv[5]*Rv[0]-Lv[6]*Rv[4]-Lv[7]*Rv[2];
        g[6] = Lv[0]*Rv[6]+Lv[1]*Rv[7]+Lv[2]*Rv[3]-Lv[3]*Rv[2]-Lv[4]*Rv[5]+Lv[5]*Rv[4]+Lv[6]*Rv[0]+Lv[7]*Rv[1];
        g[7] = Lv[0]*Rv[7]+Lv[1]*Rv[6]-Lv[2]*Rv[5]+Lv[3]*Rv[4]+Lv[4]*Rv[3]-Lv[5]*Rv[2]+Lv[6]*Rv[1]+Lv[7]*Rv[0];
        char* dst = gp_out + (size_t)b_g * 16384 + (size_t)n_g * 2;
#pragma unroll
        for (int i = 0; i < 8; ++i) *(f16*)(dst + (size_t)i * 1024) = (f16)g[i];
    }
}

// ---------------------------------------------------------------------------
// k2: out = gp @ W_out^T + b_out(e0); norm = mean_n sqrt(sum_i out^2) + eps;
//     d_out = a_norm * out / norm.  Block: 16 batches x ALL 512 channels,
//     16 waves (2 channel strips each), K=512, dbuf LDS (81KB).
//     Reads gp f16 from its own batch regions of d_out, overwrites them fp32
//     only after the K-loop (post-barrier) -> no intra/inter-block hazard.
// ---------------------------------------------------------------------------
__global__ __launch_bounds__(1024, 4) void k2_out(
    const char* gp_in, const f16* __restrict__ wo,
    const float* __restrict__ bo_p, const float* __restrict__ an_p,
    float* outp)
{
    __shared__ __align__(16) f16 As[2][8][16*32];   // 16KB
    __shared__ __align__(16) f16 Bs[2][512*32];     // 64KB
    __shared__ float red[16][16];                   // [batch][wave]

    const int b0   = blockIdx.x * 16;
    const int tid  = threadIdx.x;
    const int lane = tid & 63;
    const int wv   = tid >> 6;            // 0..15
    const int r_lo = lane & 15, s_hi = lane >> 4;

    f32x4 acc[2][8];
    const f32x4 zero = {0.f, 0.f, 0.f, 0.f};
#pragma unroll
    for (int st = 0; st < 2; ++st)
#pragma unroll
        for (int i = 0; i < 8; ++i) acc[st][i] = zero;

    // staging maps
    const int ablade = tid >> 6, arow = (tid >> 2) & 15, ac = tid & 3;  // tid<512
    const char* asrc0 = gp_in + (size_t)(b0 + arow) * 16384 + ablade * 1024 + ac * 16;
    const int aw = arow * 32 + ((ac ^ (arow & 3)) << 3);
    const int brow = tid >> 1, bc2 = (tid & 1) * 2;
    const f16* bsrc0 = wo + (size_t)brow * 512 + bc2 * 8;
    const int bw0 = brow * 32 + (((bc2    ) ^ (brow & 3)) << 3);
    const int bw1 = brow * 32 + (((bc2 + 1) ^ (brow & 3)) << 3);

    auto stage = [&](int kk, int buf) {
        if (tid < 512) {
            f16x8 v = *(const f16x8*)(asrc0 + (size_t)kk * 64);
            *(f16x8*)&As[buf][ablade][aw] = v;
        }
        const f16* bs = bsrc0 + kk * 32;
        f16x8 v0 = *(const f16x8*)(bs);
        f16x8 v1 = *(const f16x8*)(bs + 8);
        *(f16x8*)&Bs[buf][bw0] = v0;
        *(f16x8*)&Bs[buf][bw1] = v1;
    };

    const int nl0 = wv * 32 + r_lo, nl1 = nl0 + 16;
    const int boff0 = nl0 * 32 + ((s_hi ^ (nl0 & 3)) << 3);
    const int boff1 = nl1 * 32 + ((s_hi ^ (nl1 & 3)) << 3);
    const int aoff  = r_lo * 32 + ((s_hi ^ (r_lo & 3)) << 3);

    stage(0, 0);
    for (int kk = 0; kk < 16; ++kk) {
        __syncthreads();
        if (kk < 15) stage(kk + 1, (kk + 1) & 1);
        const int buf = kk & 1;
        f16x8 bf0 = *(const f16x8*)&Bs[buf][boff0];
        f16x8 bf1 = *(const f16x8*)&Bs[buf][boff1];
#pragma unroll
        for (int i = 0; i < 8; ++i) {
            f16x8 a = *(const f16x8*)&As[buf][i][aoff];
            acc[0][i] = MFMA_F16(a, bf0, acc[0][i]);
            acc[1][i] = MFMA_F16(a, bf1, acc[1][i]);
        }
    }

    const float bo0 = bo_p[nl0], bo1 = bo_p[nl1];
    const float an0 = an_p[nl0], an1 = an_p[nl1];

    // per-(batch,channel) multivector norms, summed over this lane's channels
    float partial[4];
#pragma unroll
    for (int rr = 0; rr < 4; ++rr) {
        float o = acc[0][0][rr] + bo0;
        float ss = o * o;
#pragma unroll
        for (int i = 1; i < 8; ++i) ss += acc[0][i][rr] * acc[0][i][rr];
        float s = sqrtf(ss);
        o = acc[1][0][rr] + bo1;
        ss = o * o;
#pragma unroll
        for (int i = 1; i < 8; ++i) ss += acc[1][i][rr] * acc[1][i][rr];
        partial[rr] = s + sqrtf(ss);
    }
#pragma unroll
    for (int off = 1; off < 16; off <<= 1) {
#pragma unroll
        for (int rr = 0; rr < 4; ++rr) partial[rr] += __shfl_xor(partial[rr], off);
    }
    if (r_lo == 0) {
#pragma unroll
        for (int rr = 0; rr < 4; ++rr) red[s_hi * 4 + rr][wv] = partial[rr];
    }
    __syncthreads();   // also guarantees all gp reads done before fp32 stores

#pragma unroll
    for (int rr = 0; rr < 4; ++rr) {
        float tot = 0.f;
#pragma unroll
        for (int w = 0; w < 16; ++w) tot += red[s_hi * 4 + rr][w];
        const float inv = 1.0f / (tot * (1.0f / 512.0f) + 1e-6f);
        const float sc0 = an0 * inv, sc1 = an1 * inv;
        const int b_g = b0 + s_hi * 4 + rr;
        float* dst = outp + (size_t)b_g * 4096;
        f32x4 v;
        v[0] = (acc[0][0][rr] + bo0) * sc0;
        v[1] = acc[0][1][rr] * sc0;
        v[2] = acc[0][2][rr] * sc0;
        v[3] = acc[0][3][rr] * sc0;
        *(f32x4*)(dst + (size_t)nl0 * 8) = v;
        v[0] = acc[0][4][rr] * sc0;
        v[1] = acc[0][5][rr] * sc0;
        v[2] = acc[0][6][rr] * sc0;
        v[3] = acc[0][7][rr] * sc0;
        *(f32x4*)(dst + (size_t)nl0 * 8 + 4) = v;
        v[0] = (acc[1][0][rr] + bo1) * sc1;
        v[1] = acc[1][1][rr] * sc1;
        v[2] = acc[1][2][rr] * sc1;
        v[3] = acc[1][3][rr] * sc1;
        *(f32x4*)(dst + (size_t)nl1 * 8) = v;
        v[0] = acc[1][4][rr] * sc1;
        v[1] = acc[1][5][rr] * sc1;
        v[2] = acc[1][6][rr] * sc1;
        v[3] = acc[1][7][rr] * sc1;
        *(f32x4*)(dst + (size_t)nl1 * 8 + 4) = v;
    }
}

// ---------------------------------------------------------------------------
extern "C" void kernel_launch(void* const* d_in, const int* in_sizes, int n_in,
                              void* d_out, int out_size, void* d_ws, size_t ws_size,
                              hipStream_t stream) {
    const float* x  = (const float*)d_in[0];
    const float* wl = (const float*)d_in[1];
    const float* bl = (const float*)d_in[2];
    const float* wr = (const float*)d_in[3];
    const float* br = (const float*)d_in[4];
    const float* wo = (const float*)d_in[5];
    const float* bo = (const float*)d_in[6];
    const float* an = (const float*)d_in[7];
    f16* wf = (f16*)d_ws;   // 1.5 MB of f16 weights

    hipLaunchKernelGGL(k0_cvt, dim3(1024), dim3(256), 0, stream, wl, wr, wo, wf);
    hipLaunchKernelGGL(k1_gp,  dim3(4096), dim3(512), 0, stream, x, wf, bl, br, (char*)d_out);
    hipLaunchKernelGGL(k2_out, dim3(1024), dim3(1024), 0, stream,
                       (const char*)d_out, wf + 524288, bo, an, (float*)d_out);
}